// Round 12
// baseline (329.715 us; speedup 1.0000x reference)
//
#include <hip/hip_runtime.h>
#include <hip/hip_bf16.h>

#define EMBED 1024
#define NHEADS 16
#define HDIM 64
#define SEQ 2048
#define BATCH 4
#define ROWS (BATCH * SEQ) /* 8192 */

typedef __attribute__((ext_vector_type(8))) short bf16x8;   // 8 bf16 = 4 VGPRs
typedef __attribute__((ext_vector_type(4))) float f32x4;
typedef __attribute__((ext_vector_type(2))) float f32x2;
typedef __attribute__((ext_vector_type(16))) float f32x16;
typedef __attribute__((ext_vector_type(4))) unsigned int u32x4;
typedef __attribute__((ext_vector_type(2))) unsigned int u32x2;
typedef __attribute__((ext_vector_type(2))) int i32x2;
typedef unsigned int u32;

#define SL2E 0.18033688011112042f  /* 0.125 * log2(e) */

__device__ __forceinline__ short f2bf(float f) {            // RTNA fp32->bf16 (2 ops)
    u32 u = __builtin_bit_cast(u32, f) + 0x8000u;
    return (short)(u >> 16);
}

__device__ __forceinline__ u32 pkbf(float a, float b) {     // {bf16(a)|bf16(b)<<16}, 3 ops
    u32 ua = __builtin_bit_cast(u32, a) + 0x8000u;
    u32 ub = __builtin_bit_cast(u32, b) + 0x8000u;
    return __builtin_amdgcn_perm(ua, ub, 0x03020706u);      // v_perm_b32: {a.hi16, b.hi16}
}

// single-instruction packed cvt (RTNE): a -> low16, b -> high16 (same order as pkbf)
__device__ __forceinline__ u32 cvtpk(float a, float b) {
    u32 r;
    asm("v_cvt_pk_bf16_f32 %0, %1, %2" : "=v"(r) : "v"(a), "v"(b));
    return r;
}

__device__ __forceinline__ float fexp2(float x) {
#if __has_builtin(__builtin_amdgcn_exp2f)
    return __builtin_amdgcn_exp2f(x);                       // bare v_exp_f32
#else
    return exp2f(x);
#endif
}

__device__ __forceinline__ void async16(const void* g, void* l) {
    __builtin_amdgcn_global_load_lds((const __attribute__((address_space(1))) u32*)g,
                                     (__attribute__((address_space(3))) u32*)l, 16, 0, 0);
}

// ---------- R18 fused prep: X fp32->bf16 (blocks 0..8191) + W transpose
// (blocks 8192..9215). ----------
__global__ __launch_bounds__(256) void prep(const float* __restrict__ X,
                                            short* __restrict__ Xbf,
                                            const float* __restrict__ W0,
                                            const float* __restrict__ W1,
                                            const float* __restrict__ W2,
                                            const float* __restrict__ W3,
                                            short* __restrict__ T0,
                                            short* __restrict__ T1,
                                            short* __restrict__ T2,
                                            short* __restrict__ T3) {
    const int bid = blockIdx.x;
    if (bid < 8192) {
        int i = (bid * 256 + threadIdx.x) * 4;
        float4 v = *(const float4*)&X[i];
        u32x2 o = { pkbf(v.x, v.y), pkbf(v.z, v.w) };
        *(u32x2*)&Xbf[i] = o;
        return;
    }
    const int id = bid - 8192;                 // 0..1023
    const int z = id >> 8;
    const int rem = id & 255;
    const int n0 = (rem & 15) * 64, k0 = (rem >> 4) * 64;
    const float* W = (z == 0) ? W0 : (z == 1) ? W1 : (z == 2) ? W2 : W3;
    short* WT = (z == 0) ? T0 : (z == 1) ? T1 : (z == 2) ? T2 : T3;
    const float sc = (z == 0) ? SL2E : 1.0f;
    __shared__ float T[64][65];
    const int rr = threadIdx.x >> 4, cc = (threadIdx.x & 15) * 4;
    #pragma unroll
    for (int p = 0; p < 4; ++p) {
        int r = p * 16 + rr;
        float4 v = *(const float4*)&W[(size_t)(k0 + r) * EMBED + n0 + cc];
        T[r][cc] = v.x * sc; T[r][cc + 1] = v.y * sc; T[r][cc + 2] = v.z * sc; T[r][cc + 3] = v.w * sc;
    }
    __syncthreads();
    #pragma unroll
    for (int p = 0; p < 4; ++p) {
        int r = p * 16 + rr;  // n offset
        u32x2 o = { pkbf(T[cc][r], T[cc + 1][r]), pkbf(T[cc + 2][r], T[cc + 3][r]) };
        *(u32x2*)&WT[(size_t)(n0 + r) * EMBED + k0 + cc] = o;
    }
}

// ============================================================================
// R13/R18 GEMM (unchanged): 128x256 4-phase register-reuse schedule, BK=64,
// 8 waves (2M x 4N, 64x64/wave), LDS 96 KiB, 1 blk/CU, T1 XCD swizzle,
// counted vmcnt(6).  QKV only.  R21: launched TWICE (2nd is idempotent
// duplicate purely to surface this kernel's PMC in the top-5).
// ============================================================================
__global__ __launch_bounds__(512, 2) void gemm_p128(const short* __restrict__ A,
                                                    const short* __restrict__ BT,
                                                    const float* __restrict__ b0,
                                                    const float* __restrict__ b1,
                                                    const float* __restrict__ b2,
                                                    void* __restrict__ C0,
                                                    void* __restrict__ C1,
                                                    void* __restrict__ C2,
                                                    int mode) {
    __shared__ short As[2][8192];    // [buf][128 rows][64 k], 16B chunks XOR-swizzled
    __shared__ short Bs[2][16384];   // [buf][256 cols][64 k]
    const int tid = threadIdx.x;
    const int lane = tid & 63;
    const int wid = tid >> 6;
    const int c16 = lane & 15, quad = lane >> 4, sw = c16 & 7;
    const int wm = wid >> 2, wn = wid & 3;            // 2M x 4N wave grid
    const int gx = gridDim.x;
    const int hid = blockIdx.y * gx + blockIdx.x;
    const int cpx = (gx * gridDim.y) >> 3;
    const int tle = (hid & 7) * cpx + (hid >> 3);
    const int bx = tle % gx, by = tle / gx;
    const int rowblk = by * 128, colblk = bx * 256;

    const int r0 = tid >> 3;                          // 0..63
    const int g0 = (tid & 7) ^ (r0 & 7);
    const short* aS0 = A + (size_t)(rowblk + r0) * EMBED + g0 * 8;
    const short* bS0 = BT + (size_t)(colblk + r0) * EMBED + g0 * 8;

#define STAGE_A(SBUF, V) do { \
    const short* _s = aS0 + (V) * 64; \
    async16(_s,         &As[SBUF][tid * 8]); \
    async16(_s + 65536, &As[SBUF][tid * 8 + 4096]); \
} while (0)
#define STAGE_B0(SBUF, V) do { \
    const short* _s = bS0 + (V) * 64; \
    async16(_s,         &Bs[SBUF][tid * 8]); \
    async16(_s + 65536, &Bs[SBUF][tid * 8 + 4096]); \
} while (0)
#define STAGE_B1(SBUF, V) do { \
    const short* _s = bS0 + 131072 + (V) * 64; \
    async16(_s,         &Bs[SBUF][tid * 8 + 8192]); \
    async16(_s + 65536, &Bs[SBUF][tid * 8 + 12288]); \
} while (0)

    f32x4 acc[4][4] = {};            // [m = MH*2+fm][n = NH*2+fn], static idx
    bf16x8 aU[2][2], bE[2][2], bO[2][2];

#define LDA(BUF, MH) do { \
    _Pragma("unroll") \
    for (int fm = 0; fm < 2; ++fm) { \
        const int row = wm * 64 + (MH) * 32 + fm * 16 + c16; \
        _Pragma("unroll") \
        for (int ks = 0; ks < 2; ++ks) \
            aU[fm][ks] = *(const bf16x8*)&As[BUF][row * 64 + ((ks * 4 + quad) ^ sw) * 8]; \
    } \
} while (0)
#define LDB(BUF, NH, DST) do { \
    _Pragma("unroll") \
    for (int fn = 0; fn < 2; ++fn) { \
        const int col = wn * 64 + (NH) * 32 + fn * 16 + c16; \
        _Pragma("unroll") \
        for (int ks = 0; ks < 2; ++ks) \
            DST[fn][ks] = *(const bf16x8*)&Bs[BUF][col * 64 + ((ks * 4 + quad) ^ sw) * 8]; \
    } \
} while (0)
#define MM(MB, NB, BM_) do { \
    _Pragma("unroll") \
    for (int fm = 0; fm < 2; ++fm) \
        _Pragma("unroll") \
        for (int fn = 0; fn < 2; ++fn) \
            _Pragma("unroll") \
            for (int ks = 0; ks < 2; ++ks) \
                acc[(MB) + fm][(NB) + fn] = \
                    __builtin_amdgcn_mfma_f32_16x16x32_bf16(aU[fm][ks], BM_[fn][ks], \
                        acc[(MB) + fm][(NB) + fn], 0, 0, 0); \
} while (0)
#define PH_MID() do { \
    __builtin_amdgcn_s_barrier(); \
    asm volatile("s_waitcnt lgkmcnt(0)" ::: "memory"); \
    __builtin_amdgcn_s_setprio(1); \
} while (0)
#define PH_END(VM) do { \
    __builtin_amdgcn_s_setprio(0); \
    if (VM) asm volatile("s_waitcnt vmcnt(6)" ::: "memory"); \
    __builtin_amdgcn_s_barrier(); \
} while (0)

    // prologue: tile0 (buf0) + tile1 (buf1) staged; wait tile0 (6 outstanding)
    STAGE_B0(0, 0); STAGE_A(0, 0); STAGE_B1(0, 0);
    STAGE_B0(1, 1); STAGE_A(1, 1); STAGE_B1(1, 1);
    asm volatile("s_waitcnt vmcnt(6)" ::: "memory");
    __builtin_amdgcn_s_barrier();

    #pragma unroll 1
    for (int it = 0; it < 8; ++it) {
        const int u = 2 * it;
        const int v2 = (u + 2) & 15, v3 = (u + 3) & 15;
        // ---- tile u (buf0); stage tile u+2 -> buf0 ----
        LDA(0, 0); LDB(0, 0, bE);                     PH_MID(); MM(0, 0, bE); PH_END(0);
        LDB(0, 1, bO);            STAGE_B0(0, v2);    PH_MID(); MM(0, 2, bO); PH_END(0);
        LDA(0, 1);                STAGE_B1(0, v2);    PH_MID(); MM(2, 2, bO); PH_END(0);
        /* no ds_reads */         STAGE_A(0, v2);     PH_MID(); MM(2, 0, bE); PH_END(1);
        // ---- tile u+1 (buf1); stage tile u+3 -> buf1 ----
        LDA(1, 0); LDB(1, 0, bE);                     PH_MID(); MM(0, 0, bE); PH_END(0);
        LDB(1, 1, bO);            STAGE_B0(1, v3);    PH_MID(); MM(0, 2, bO); PH_END(0);
        LDA(1, 1);                STAGE_B1(1, v3);    PH_MID(); MM(2, 2, bO); PH_END(0);
        /* no ds_reads */         STAGE_A(1, v3);     PH_MID(); MM(2, 0, bE); PH_END(1);
    }

    asm volatile("s_waitcnt vmcnt(0)" ::: "memory");

    const int rb0 = rowblk + wm * 64 + quad * 4;
    const int cb0 = wn * 64 + c16;
    if (mode == 0) {
        const int z = colblk >> 10;
        const int cm = colblk & 1023;
        const float* bias = (z == 0) ? b0 : (z == 1) ? b1 : b2;
        if (z == 2) {
            short* Vt = (short*)C2;
            #pragma unroll
            for (int m = 0; m < 4; ++m) {
                const int row = rb0 + (m >> 1) * 32 + (m & 1) * 16;
                const int b = row >> 11, s = row & 2047;
                #pragma unroll
                for (int n = 0; n < 4; ++n) {
                    const int cv = cm + cb0 + (n >> 1) * 32 + (n & 1) * 16;
                    const int head = cv >> 6, d = cv & 63;
                    const float bv = bias[cv];
                    u32x2 o = { pkbf(acc[m][n][0] + bv, acc[m][n][1] + bv),
                                pkbf(acc[m][n][2] + bv, acc[m][n][3] + bv) };
                    *(u32x2*)&Vt[((size_t)(b * NHEADS + head) * HDIM + d) * SEQ + s] = o;
                }
            }
        } else {
            short* Cq = (short*)((z == 0) ? C0 : C1);
            const float bsc = (z == 0) ? SL2E : 1.0f;
            #pragma unroll
            for (int m = 0; m < 4; ++m) {
                const int row = rb0 + (m >> 1) * 32 + (m & 1) * 16;
                #pragma unroll
                for (int n = 0; n < 4; ++n) {
                    const int col = cm + cb0 + (n >> 1) * 32 + (n & 1) * 16;
                    const float bv = bias[col] * bsc;
                    #pragma unroll
                    for (int r = 0; r < 4; ++r)
                        Cq[(size_t)(row + r) * EMBED + col] = f2bf(acc[m][n][r] + bv);
                }
            }
        }
    } else {
        float* Co = (float*)C0;
        #pragma unroll
        for (int m = 0; m < 4; ++m) {
            const int row = rb0 + (m >> 1) * 32 + (m & 1) * 16;
            #pragma unroll
            for (int n = 0; n < 4; ++n) {
                const int col = colblk + cb0 + (n >> 1) * 32 + (n & 1) * 16;
                const float bv = b0[col];
                #pragma unroll
                for (int r = 0; r < 4; ++r)
                    Co[(size_t)(row + r) * EMBED + col] = acc[m][n][r] + bv;
            }
        }
    }
#undef PH_END
#undef PH_MID
#undef MM
#undef LDB
#undef LDA
#undef STAGE_B1
#undef STAGE_B0
#undef STAGE_A
}

// ============================================================================
// R20 out-proj GEMM (unchanged): 128x128 tile, 8 waves, BK=64, LDS 64 KiB
// dbuf, 2 blocks/CU, attn-style stage pattern.  fp32 out + bias.
// ============================================================================
__global__ __launch_bounds__(512, 2) void gemm_k64(const short* __restrict__ A,
                                                   const short* __restrict__ BT,
                                                   const float* __restrict__ bias,
                                                   float* __restrict__ C) {
    __shared__ short As[2][8192];    // [buf][128 rows][64 k], 16 KB each
    __shared__ short Bs[2][8192];    // [buf][128 cols][64 k]
    const int tid = threadIdx.x;
    const int lane = tid & 63, wid = tid >> 6;
    const int c16 = lane & 15, quad = lane >> 4, sw = c16 & 7;
    const int wm = wid >> 2, wn = wid & 3;    // per-wave 64 rows x 32 cols
    // T1 swizzle: 512 blocks, % 8 == 0
    const int gx = gridDim.x;
    const int hid = blockIdx.y * gx + blockIdx.x;
    const int cpx = (gx * gridDim.y) >> 3;
    const int tle = (hid & 7) * cpx + (hid >> 3);
    const int bx = tle % gx, by = tle / gx;
    const int rowblk = by * 128, colblk = bx * 128;

    const int r0 = tid >> 3;                  // 0..63
    const int g0 = (tid & 7) ^ (r0 & 7);
    const short* aS = A + (size_t)(rowblk + r0) * EMBED + g0 * 8;
    const short* bS = BT + (size_t)(colblk + r0) * EMBED + g0 * 8;

#define STG(SBUF, V) do { \
    const short* _a = aS + (V) * 64; \
    const short* _b = bS + (V) * 64; \
    async16(_a,         &As[SBUF][tid * 8]); \
    async16(_a + 65536, &As[SBUF][tid * 8 + 4096]); \
    async16(_b,         &Bs[SBUF][tid * 8]); \
    async16(_b + 65536, &Bs[SBUF][tid * 8 + 4096]); \
} while (0)

    f32x4 acc[4][2] = {};

    STG(0, 0);
    asm volatile("s_waitcnt vmcnt(0)" ::: "memory");
    __builtin_amdgcn_s_barrier();

    #pragma unroll 2
    for (int t = 0; t < 16; ++t) {
        const int cur = t & 1;
        if (t < 15) STG(cur ^ 1, t + 1);      // issue next-tile DMAs early
        bf16x8 af[4][2], bfv[2][2];
        #pragma unroll
        for (int fm = 0; fm < 4; ++fm) {
            const int row = wm * 64 + fm * 16 + c16;
            #pragma unroll
            for (int ks = 0; ks < 2; ++ks)
                af[fm][ks] = *(const bf16x8*)&As[cur][row * 64 + ((ks * 4 + quad) ^ sw) * 8];
        }
        #pragma unroll
        for (int fn = 0; fn < 2; ++fn) {
            const int col = wn * 32 + fn * 16 + c16;
            #pragma unroll
            for (int ks = 0; ks < 2; ++ks)
                bfv[fn][ks] = *(const bf16x8*)&Bs[cur][col * 64 + ((ks * 4 + quad) ^ sw) * 8];
        }
        __builtin_amdgcn_s_setprio(1);
        #pragma unroll
        for (int fm = 0; fm < 4; ++fm)
            #pragma unroll
            for (int fn = 0; fn < 2; ++fn)
                #pragma unroll
                for (int ks = 0; ks < 2; ++ks)
                    acc[fm][fn] = __builtin_amdgcn_mfma_f32_16x16x32_bf16(af[fm][ks], bfv[fn][ks], acc[fm][fn], 0, 0, 0);
        __builtin_amdgcn_s_setprio(0);
        asm volatile("s_waitcnt vmcnt(0)" ::: "memory");   // next tile landed (hidden under MFMA)
        __builtin_amdgcn_s_barrier();
    }

    // epilogue: C/D frag col = lane&15, row = quad*4 + reg
    const int rb0 = rowblk + wm * 64 + quad * 4;
    const int cb0 = colblk + wn * 32 + c16;
    #pragma unroll
    for (int fm = 0; fm < 4; ++fm) {
        const int row = rb0 + fm * 16;
        #pragma unroll
        for (int fn = 0; fn < 2; ++fn) {
            const int col = cb0 + fn * 16;
            const float bv = bias[col];
            #pragma unroll
            for (int r = 0; r < 4; ++r)
                C[(size_t)(row + r) * EMBED + col] = acc[fm][fn][r] + bv;
        }
    }
#undef STG
}

// ---------- MFMA flash attention v5.1 (unchanged — control: ~76 us,
// MfmaUtil 40 + VALUBusy 50 at 4 blocks/CU; cvt_pk P-pack). ----------
__global__ __launch_bounds__(256, 4) void attn_mfma(const short* __restrict__ Qb,
                                                    const short* __restrict__ Kb,
                                                    const short* __restrict__ Vt,
                                                    short* __restrict__ Ob) {
    __shared__ short SH[16384];      // kb[2] @ 0/4096, vb[2] @ 8192/12288 (shorts)
    const int tid = threadIdx.x;
    const int wave = tid >> 6, lane = tid & 63;
    const int l31 = lane & 31, h = lane >> 5;
    const int swz = l31 & 7;
    // T1 swizzle: grid (16 qb, 64 bh) = 1024 blocks
    const int hid = blockIdx.y * 16 + blockIdx.x;
    const int tle = (hid & 7) * 128 + (hid >> 3);
    const int qb = tle & 15, bh = tle >> 4;
    const int b = bh >> 4, hd = bh & 15;
    const size_t base = (size_t)b * SEQ * EMBED + (size_t)hd * HDIM;
    const size_t vbase = (size_t)bh * HDIM * SEQ;
    const int q0 = qb * 128;

    // Q B-frags for the whole kernel: n=q=l31, k(d) = ks*16 + h*8 + j
    bf16x8 qf[4];
    #pragma unroll
    for (int ks = 0; ks < 4; ++ks)
        qf[ks] = *(const bf16x8*)&Qb[base + (size_t)(q0 + wave * 32 + l31) * EMBED + ks * 16 + h * 8];

    // hoisted staging pointers (advance by constant per staged tile)
    const short* kp[2];
    const short* vp[2];
    int ldofs[2];
    #pragma unroll
    for (int it = 0; it < 2; ++it) {
        int ci = (it * 4 + wave) * 64 + lane;
        int row = ci >> 3, g = (ci & 7) ^ (row & 7);
        kp[it] = Kb + base + (size_t)row * EMBED + g * 8;
        vp[it] = Vt + vbase + (size_t)row * SEQ + g * 8;
        ldofs[it] = (it * 4 + wave) * 512;          // wave-uniform LDS base
    }

#define STAGE_KV(J) do { \
    async16(kp[0], &SH[(J) * 4096 + ldofs[0]]); \
    async16(kp[1], &SH[(J) * 4096 + ldofs[1]]); \
    async16(vp[0], &SH[8192 + (J) * 4096 + ldofs[0]]); \
    async16(vp[1], &SH[8192 + (J) * 4096 + ldofs[1]]); \
    kp[0] += 64 * EMBED; kp[1] += 64 * EMBED; \
    vp[0] += 64; vp[1] += 64; \
} while (0)

    f32x16 O[2] = {};
    f32x2 ls = {0.0f, 0.0f};

    // prologue: stage tile 0 into buf0
    STAGE_KV(0);
    asm volatile("s_waitcnt vmcnt(0)" ::: "memory");
    __builtin_amdgcn_s_barrier();

// One K/V tile from buffer CUR; optionally stage tile t+1 into buf NXT first.
// Per-nt half: QK(nt) 4 MFMA -> exp/pack (8 exp-pairs, 8 pk words via cvt_pk)
// -> PV steps ks=2nt,2nt+1 (4 MFMA).  S-liveness = one f32x16, pk = 8 regs.
#define ATT_TILE(CUR, NXT, DO_STAGE) do { \
    if (DO_STAGE) STAGE_KV(NXT); \
    _Pragma("unroll") \
    for (int nt = 0; nt < 2; ++nt) { \
        f32x16 st = {0.0f, 0.0f, 0.0f, 0.0f, 0.0f, 0.0f, 0.0f, 0.0f, \
                     0.0f, 0.0f, 0.0f, 0.0f, 0.0f, 0.0f, 0.0f, 0.0f}; \
        __builtin_amdgcn_s_setprio(1); \
        _Pragma("unroll") \
        for (int ks = 0; ks < 4; ++ks) { \
            bf16x8 ak = *(const bf16x8*)&SH[(CUR) * 4096 + (nt * 32 + l31) * 64 + ((ks * 2 + h) ^ swz) * 8]; \
            st = __builtin_amdgcn_mfma_f32_32x32x16_bf16(ak, qf[ks], st, 0, 0, 0); \
        } \
        __builtin_amdgcn_s_setprio(0); \
        u32 pk[8]; \
        _Pragma("unroll") \
        for (int i = 0; i < 8; ++i) { \
            float e0 = fexp2(st[2 * i]), e1 = fexp2(st[2 * i + 1]); \
            f32x2 e = { e0, e1 }; \
            ls += e; \
            pk[i] = cvtpk(e0, e1); \
        } \
        __builtin_amdgcn_s_setprio(1); \
        _Pragma("unroll") \
        for (int kk = 0; kk < 2; ++kk) { \
            const int ks = nt * 2 + kk, bs = kk * 4; \
            u32x4 fr; \
            i32x2 sA = __builtin_amdgcn_permlane32_swap((int)pk[bs + 0], (int)pk[bs + 2], false, false); \
            i32x2 sB = __builtin_amdgcn_permlane32_swap((int)pk[bs + 1], (int)pk[bs + 3], false, false); \
            fr.x = (u32)sA.x; fr.y = (u32)sB.x; fr.z = (u32)sA.y; fr.w = (u32)sB.y; \
            bf16x8 pf = __builtin_bit_cast(bf16x8, fr); \
            _Pragma("unroll") \
            for (int mt = 0; mt < 2; ++mt) { \
                bf16x8 vf = *(const bf16x8*)&SH[8192 + (CUR) * 4096 + (mt * 32 + l31) * 64 + ((ks * 2 + h) ^ swz) * 8]; \
                O[mt] = __builtin_amdgcn_mfma_f32_32x32x16_bf16(vf, pf, O[mt], 0, 0, 0); \
            } \
        } \
        __builtin_amdgcn_s_setprio(0); \
    } \
    asm volatile("s_waitcnt vmcnt(0)" ::: "memory"); \
    __builtin_amdgcn_s_barrier(); \
} while (0)

    // tiles 0..30 stage t+1; tile 31 computes only
    #pragma unroll 1
    for (int t = 0; t < 30; t += 2) {
        ATT_TILE(0, 1, 1);
        ATT_TILE(1, 0, 1);
    }
    ATT_TILE(0, 1, 1);   // t=30, stages 31 -> buf1
    ATT_TILE(1, 0, 0);   // t=31

#undef ATT_TILE
#undef STAGE_KV

    // finalize: partner lane holds the other half of this q's key-sum
    float lsum = ls.x + ls.y;
    lsum += __shfl_xor(lsum, 32);
    float inv = 1.0f / lsum;

    // O^T[d][q]: col=q=l31, d = mt*32 + (reg&3) + 8*(reg>>2) + 4h.
    // Write bf16 to LDS (XOR-swizzled 8B units), then read rows -> coalesced.
    const int wbase = wave * 2048;
    #pragma unroll
    for (int mt = 0; mt < 2; ++mt)
        #pragma unroll
        for (int m = 0; m < 4; ++m) {
            u32x2 wv;
            wv.x = pkbf(O[mt][4 * m + 0] * inv, O[mt][4 * m + 1] * inv);
            wv.y = pkbf(O[mt][4 * m + 2] * inv, O[mt][4 * m + 3] * inv);
            int u = mt * 8 + 2 * m + h;               // 8B unit index (d = u*4)
            int su = u ^ ((l31 & 7) << 1);
            *(u32x2*)&SH[wbase + l31 * 64 + su * 4] = wv;
        }
    __syncthreads();
    // full tile = 1024 x 16B chunks (4 waves x 32 q x 8 d-chunks)
    #pragma unroll
    for (int p = 0; p < 4; ++p) {
        int ci = p * 256 + tid;
        int wq = ci >> 8, rem = ci & 255;
        int r = rem >> 3, cch = rem & 7;
        int su = (2 * cch) ^ ((r & 7) << 1);
        bf16x8 val = *(const bf16x8*)&SH[wq * 2048 + r * 64 + su * 4];
        *(bf16x8*)&Ob[base + (size_t)(q0 + wq * 32 + r) * EMBED + cch * 8] = val;
    }
}

extern "C" void kernel_launch(void* const* d_in, const int* in_sizes, int n_in,
                              void* d_out, int out_size, void* d_ws, size_t ws_size,
                              hipStream_t stream)
{
    const float* X  = (const float*)d_in[0];
    const float* Wq = (const float*)d_in[1];
    const float* bq = (const float*)d_in[2];
    const float* Wk = (const float*)d_in[3];
    const float* bk = (const float*)d_in[4];
    const float* Wv = (const float*)d_in[5];
    const float* bv = (const float*)d_in[6];
    const float* Wo = (const float*)d_in[7];
    const float* bo = (const float*)d_in[8];
    float* out = (float*)d_out;

    const size_t NE = (size_t)ROWS * EMBED;       // 8M elements
    short* Xbf = (short*)d_ws;                    // 16 MB
    short* Qb  = Xbf + NE;                        // 16 MB (also attention O)
    short* Kb  = Qb + NE;                         // 16 MB
    short* Vtb = Kb + NE;                         // 16 MB  [bh][d][s]
    short* WqT = Vtb + NE;                        // 2 MB each; WqT/WkT/WvT are
    short* WkT = WqT + (size_t)EMBED * EMBED;     //   CONTIGUOUS = combined
    short* WvT = WkT + (size_t)EMBED * EMBED;     //   Wqkv^T [3072][1024]
    short* WoT = WvT + (size_t)EMBED * EMBED;     // total 72 MB

    // fused convert + weight transpose: 8192 + 1024 blocks, one dispatch
    prep<<<9216, 256, 0, stream>>>(X, Xbf, Wq, Wk, Wv, Wo, WqT, WkT, WvT, WoT);

    // combined QKV: grid (3072/256, 8192/128) = 768 blocks = 3 exact rounds
    dim3 gq(12, 64, 1);
    gemm_p128<<<gq, 512, 0, stream>>>(Xbf, WqT, bq, bk, bv, Qb, Kb, Vtb, 0);
    // R21 INSTRUMENTATION: duplicate (idempotent) QKV dispatch so gemm_p128
    // surfaces in the rocprof top-5 with full PMC.  Costs ~78 us this round;
    // R22 will drop it and apply the counter-guided fix.
    gemm_p128<<<gq, 512, 0, stream>>>(Xbf, WqT, bq, bk, bv, Qb, Kb, Vtb, 0);

    dim3 gt(SEQ / 128, BATCH * NHEADS);           // (16, 64)
    attn_mfma<<<gt, 256, 0, stream>>>(Qb, Kb, Vtb, Qb);   // O aliases Qb

    // out-proj: grid (1024/128, 8192/128) = 512 blocks = 2 blocks/CU
    dim3 gg(8, 64, 1);
    gemm_k64<<<gg, 512, 0, stream>>>(Qb, WoT, bo, out);
}

// Round 13
// 275.119 us; speedup vs baseline: 1.1984x; 1.1984x over previous
//
#include <hip/hip_runtime.h>
#include <hip/hip_bf16.h>

#define EMBED 1024
#define NHEADS 16
#define HDIM 64
#define SEQ 2048
#define BATCH 4
#define ROWS (BATCH * SEQ) /* 8192 */

typedef __attribute__((ext_vector_type(8))) short bf16x8;   // 8 bf16 = 4 VGPRs
typedef __attribute__((ext_vector_type(4))) float f32x4;
typedef __attribute__((ext_vector_type(2))) float f32x2;
typedef __attribute__((ext_vector_type(16))) float f32x16;
typedef __attribute__((ext_vector_type(4))) unsigned int u32x4;
typedef __attribute__((ext_vector_type(2))) unsigned int u32x2;
typedef __attribute__((ext_vector_type(2))) int i32x2;
typedef unsigned int u32;

#define SL2E 0.18033688011112042f  /* 0.125 * log2(e) */

__device__ __forceinline__ short f2bf(float f) {            // RTNA fp32->bf16 (2 ops)
    u32 u = __builtin_bit_cast(u32, f) + 0x8000u;
    return (short)(u >> 16);
}

__device__ __forceinline__ u32 pkbf(float a, float b) {     // {bf16(a)|bf16(b)<<16}, 3 ops
    u32 ua = __builtin_bit_cast(u32, a) + 0x8000u;
    u32 ub = __builtin_bit_cast(u32, b) + 0x8000u;
    return __builtin_amdgcn_perm(ua, ub, 0x03020706u);      // v_perm_b32: {a.hi16, b.hi16}
}

// single-instruction packed cvt (RTNE): a -> low16, b -> high16 (same order as pkbf)
__device__ __forceinline__ u32 cvtpk(float a, float b) {
    u32 r;
    asm("v_cvt_pk_bf16_f32 %0, %1, %2" : "=v"(r) : "v"(a), "v"(b));
    return r;
}

__device__ __forceinline__ float fexp2(float x) {
#if __has_builtin(__builtin_amdgcn_exp2f)
    return __builtin_amdgcn_exp2f(x);                       // bare v_exp_f32
#else
    return exp2f(x);
#endif
}

__device__ __forceinline__ void async16(const void* g, void* l) {
    __builtin_amdgcn_global_load_lds((const __attribute__((address_space(1))) u32*)g,
                                     (__attribute__((address_space(3))) u32*)l, 16, 0, 0);
}

// ---------- R18 fused prep: X fp32->bf16 (blocks 0..8191) + W transpose
// (blocks 8192..9215). ----------
__global__ __launch_bounds__(256) void prep(const float* __restrict__ X,
                                            short* __restrict__ Xbf,
                                            const float* __restrict__ W0,
                                            const float* __restrict__ W1,
                                            const float* __restrict__ W2,
                                            const float* __restrict__ W3,
                                            short* __restrict__ T0,
                                            short* __restrict__ T1,
                                            short* __restrict__ T2,
                                            short* __restrict__ T3) {
    const int bid = blockIdx.x;
    if (bid < 8192) {
        int i = (bid * 256 + threadIdx.x) * 4;
        float4 v = *(const float4*)&X[i];
        u32x2 o = { pkbf(v.x, v.y), pkbf(v.z, v.w) };
        *(u32x2*)&Xbf[i] = o;
        return;
    }
    const int id = bid - 8192;                 // 0..1023
    const int z = id >> 8;
    const int rem = id & 255;
    const int n0 = (rem & 15) * 64, k0 = (rem >> 4) * 64;
    const float* W = (z == 0) ? W0 : (z == 1) ? W1 : (z == 2) ? W2 : W3;
    short* WT = (z == 0) ? T0 : (z == 1) ? T1 : (z == 2) ? T2 : T3;
    const float sc = (z == 0) ? SL2E : 1.0f;
    __shared__ float T[64][65];
    const int rr = threadIdx.x >> 4, cc = (threadIdx.x & 15) * 4;
    #pragma unroll
    for (int p = 0; p < 4; ++p) {
        int r = p * 16 + rr;
        float4 v = *(const float4*)&W[(size_t)(k0 + r) * EMBED + n0 + cc];
        T[r][cc] = v.x * sc; T[r][cc + 1] = v.y * sc; T[r][cc + 2] = v.z * sc; T[r][cc + 3] = v.w * sc;
    }
    __syncthreads();
    #pragma unroll
    for (int p = 0; p < 4; ++p) {
        int r = p * 16 + rr;  // n offset
        u32x2 o = { pkbf(T[cc][r], T[cc + 1][r]), pkbf(T[cc + 2][r], T[cc + 3][r]) };
        *(u32x2*)&WT[(size_t)(n0 + r) * EMBED + k0 + cc] = o;
    }
}

// ============================================================================
// R13/R18 GEMM (unchanged): 128x256 4-phase register-reuse schedule, BK=64,
// 8 waves (2M x 4N, 64x64/wave), LDS 96 KiB, 1 blk/CU, T1 XCD swizzle,
// counted vmcnt(6).  QKV only.  Measured R21 (duplicate-delta): 73.8 us
// = 698 TF.
// ============================================================================
__global__ __launch_bounds__(512, 2) void gemm_p128(const short* __restrict__ A,
                                                    const short* __restrict__ BT,
                                                    const float* __restrict__ b0,
                                                    const float* __restrict__ b1,
                                                    const float* __restrict__ b2,
                                                    void* __restrict__ C0,
                                                    void* __restrict__ C1,
                                                    void* __restrict__ C2,
                                                    int mode) {
    __shared__ short As[2][8192];    // [buf][128 rows][64 k], 16B chunks XOR-swizzled
    __shared__ short Bs[2][16384];   // [buf][256 cols][64 k]
    const int tid = threadIdx.x;
    const int lane = tid & 63;
    const int wid = tid >> 6;
    const int c16 = lane & 15, quad = lane >> 4, sw = c16 & 7;
    const int wm = wid >> 2, wn = wid & 3;            // 2M x 4N wave grid
    const int gx = gridDim.x;
    const int hid = blockIdx.y * gx + blockIdx.x;
    const int cpx = (gx * gridDim.y) >> 3;
    const int tle = (hid & 7) * cpx + (hid >> 3);
    const int bx = tle % gx, by = tle / gx;
    const int rowblk = by * 128, colblk = bx * 256;

    const int r0 = tid >> 3;                          // 0..63
    const int g0 = (tid & 7) ^ (r0 & 7);
    const short* aS0 = A + (size_t)(rowblk + r0) * EMBED + g0 * 8;
    const short* bS0 = BT + (size_t)(colblk + r0) * EMBED + g0 * 8;

#define STAGE_A(SBUF, V) do { \
    const short* _s = aS0 + (V) * 64; \
    async16(_s,         &As[SBUF][tid * 8]); \
    async16(_s + 65536, &As[SBUF][tid * 8 + 4096]); \
} while (0)
#define STAGE_B0(SBUF, V) do { \
    const short* _s = bS0 + (V) * 64; \
    async16(_s,         &Bs[SBUF][tid * 8]); \
    async16(_s + 65536, &Bs[SBUF][tid * 8 + 4096]); \
} while (0)
#define STAGE_B1(SBUF, V) do { \
    const short* _s = bS0 + 131072 + (V) * 64; \
    async16(_s,         &Bs[SBUF][tid * 8 + 8192]); \
    async16(_s + 65536, &Bs[SBUF][tid * 8 + 12288]); \
} while (0)

    f32x4 acc[4][4] = {};            // [m = MH*2+fm][n = NH*2+fn], static idx
    bf16x8 aU[2][2], bE[2][2], bO[2][2];

#define LDA(BUF, MH) do { \
    _Pragma("unroll") \
    for (int fm = 0; fm < 2; ++fm) { \
        const int row = wm * 64 + (MH) * 32 + fm * 16 + c16; \
        _Pragma("unroll") \
        for (int ks = 0; ks < 2; ++ks) \
            aU[fm][ks] = *(const bf16x8*)&As[BUF][row * 64 + ((ks * 4 + quad) ^ sw) * 8]; \
    } \
} while (0)
#define LDB(BUF, NH, DST) do { \
    _Pragma("unroll") \
    for (int fn = 0; fn < 2; ++fn) { \
        const int col = wn * 64 + (NH) * 32 + fn * 16 + c16; \
        _Pragma("unroll") \
        for (int ks = 0; ks < 2; ++ks) \
            DST[fn][ks] = *(const bf16x8*)&Bs[BUF][col * 64 + ((ks * 4 + quad) ^ sw) * 8]; \
    } \
} while (0)
#define MM(MB, NB, BM_) do { \
    _Pragma("unroll") \
    for (int fm = 0; fm < 2; ++fm) \
        _Pragma("unroll") \
        for (int fn = 0; fn < 2; ++fn) \
            _Pragma("unroll") \
            for (int ks = 0; ks < 2; ++ks) \
                acc[(MB) + fm][(NB) + fn] = \
                    __builtin_amdgcn_mfma_f32_16x16x32_bf16(aU[fm][ks], BM_[fn][ks], \
                        acc[(MB) + fm][(NB) + fn], 0, 0, 0); \
} while (0)
#define PH_MID() do { \
    __builtin_amdgcn_s_barrier(); \
    asm volatile("s_waitcnt lgkmcnt(0)" ::: "memory"); \
    __builtin_amdgcn_s_setprio(1); \
} while (0)
#define PH_END(VM) do { \
    __builtin_amdgcn_s_setprio(0); \
    if (VM) asm volatile("s_waitcnt vmcnt(6)" ::: "memory"); \
    __builtin_amdgcn_s_barrier(); \
} while (0)

    // prologue: tile0 (buf0) + tile1 (buf1) staged; wait tile0 (6 outstanding)
    STAGE_B0(0, 0); STAGE_A(0, 0); STAGE_B1(0, 0);
    STAGE_B0(1, 1); STAGE_A(1, 1); STAGE_B1(1, 1);
    asm volatile("s_waitcnt vmcnt(6)" ::: "memory");
    __builtin_amdgcn_s_barrier();

    #pragma unroll 1
    for (int it = 0; it < 8; ++it) {
        const int u = 2 * it;
        const int v2 = (u + 2) & 15, v3 = (u + 3) & 15;
        // ---- tile u (buf0); stage tile u+2 -> buf0 ----
        LDA(0, 0); LDB(0, 0, bE);                     PH_MID(); MM(0, 0, bE); PH_END(0);
        LDB(0, 1, bO);            STAGE_B0(0, v2);    PH_MID(); MM(0, 2, bO); PH_END(0);
        LDA(0, 1);                STAGE_B1(0, v2);    PH_MID(); MM(2, 2, bO); PH_END(0);
        /* no ds_reads */         STAGE_A(0, v2);     PH_MID(); MM(2, 0, bE); PH_END(1);
        // ---- tile u+1 (buf1); stage tile u+3 -> buf1 ----
        LDA(1, 0); LDB(1, 0, bE);                     PH_MID(); MM(0, 0, bE); PH_END(0);
        LDB(1, 1, bO);            STAGE_B0(1, v3);    PH_MID(); MM(0, 2, bO); PH_END(0);
        LDA(1, 1);                STAGE_B1(1, v3);    PH_MID(); MM(2, 2, bO); PH_END(0);
        /* no ds_reads */         STAGE_A(1, v3);     PH_MID(); MM(2, 0, bE); PH_END(1);
    }

    asm volatile("s_waitcnt vmcnt(0)" ::: "memory");

    const int rb0 = rowblk + wm * 64 + quad * 4;
    const int cb0 = wn * 64 + c16;
    if (mode == 0) {
        const int z = colblk >> 10;
        const int cm = colblk & 1023;
        const float* bias = (z == 0) ? b0 : (z == 1) ? b1 : b2;
        if (z == 2) {
            short* Vt = (short*)C2;
            #pragma unroll
            for (int m = 0; m < 4; ++m) {
                const int row = rb0 + (m >> 1) * 32 + (m & 1) * 16;
                const int b = row >> 11, s = row & 2047;
                #pragma unroll
                for (int n = 0; n < 4; ++n) {
                    const int cv = cm + cb0 + (n >> 1) * 32 + (n & 1) * 16;
                    const int head = cv >> 6, d = cv & 63;
                    const float bv = bias[cv];
                    u32x2 o = { pkbf(acc[m][n][0] + bv, acc[m][n][1] + bv),
                                pkbf(acc[m][n][2] + bv, acc[m][n][3] + bv) };
                    *(u32x2*)&Vt[((size_t)(b * NHEADS + head) * HDIM + d) * SEQ + s] = o;
                }
            }
        } else {
            short* Cq = (short*)((z == 0) ? C0 : C1);
            const float bsc = (z == 0) ? SL2E : 1.0f;
            #pragma unroll
            for (int m = 0; m < 4; ++m) {
                const int row = rb0 + (m >> 1) * 32 + (m & 1) * 16;
                #pragma unroll
                for (int n = 0; n < 4; ++n) {
                    const int col = cm + cb0 + (n >> 1) * 32 + (n & 1) * 16;
                    const float bv = bias[col] * bsc;
                    #pragma unroll
                    for (int r = 0; r < 4; ++r)
                        Cq[(size_t)(row + r) * EMBED + col] = f2bf(acc[m][n][r] + bv);
                }
            }
        }
    } else {
        float* Co = (float*)C0;
        #pragma unroll
        for (int m = 0; m < 4; ++m) {
            const int row = rb0 + (m >> 1) * 32 + (m & 1) * 16;
            #pragma unroll
            for (int n = 0; n < 4; ++n) {
                const int col = colblk + cb0 + (n >> 1) * 32 + (n & 1) * 16;
                const float bv = b0[col];
                #pragma unroll
                for (int r = 0; r < 4; ++r)
                    Co[(size_t)(row + r) * EMBED + col] = acc[m][n][r] + bv;
            }
        }
    }
#undef PH_END
#undef PH_MID
#undef MM
#undef LDB
#undef LDA
#undef STAGE_B1
#undef STAGE_B0
#undef STAGE_A
}

// ============================================================================
// R20 out-proj GEMM (unchanged): 128x128 tile, 8 waves, BK=64, LDS 64 KiB
// dbuf, 2 blocks/CU, attn-style stage pattern.  fp32 out + bias.
// R22: launched TWICE (idempotent duplicate) to measure its duration via
// total-delta vs the 255.9-us R20 config.  Pre-committed fork:
//   X <= 15 us -> out-proj healthy; residual ~80us is harness overhead;
//                 R23 attacks QKV (73.8us measured) + attn.
//   X >= 50 us -> out-proj pathological; R23 rewrites as split-K.
// ============================================================================
__global__ __launch_bounds__(512, 2) void gemm_k64(const short* __restrict__ A,
                                                   const short* __restrict__ BT,
                                                   const float* __restrict__ bias,
                                                   float* __restrict__ C) {
    __shared__ short As[2][8192];    // [buf][128 rows][64 k], 16 KB each
    __shared__ short Bs[2][8192];    // [buf][128 cols][64 k]
    const int tid = threadIdx.x;
    const int lane = tid & 63, wid = tid >> 6;
    const int c16 = lane & 15, quad = lane >> 4, sw = c16 & 7;
    const int wm = wid >> 2, wn = wid & 3;    // per-wave 64 rows x 32 cols
    // T1 swizzle: 512 blocks, % 8 == 0
    const int gx = gridDim.x;
    const int hid = blockIdx.y * gx + blockIdx.x;
    const int cpx = (gx * gridDim.y) >> 3;
    const int tle = (hid & 7) * cpx + (hid >> 3);
    const int bx = tle % gx, by = tle / gx;
    const int rowblk = by * 128, colblk = bx * 128;

    const int r0 = tid >> 3;                  // 0..63
    const int g0 = (tid & 7) ^ (r0 & 7);
    const short* aS = A + (size_t)(rowblk + r0) * EMBED + g0 * 8;
    const short* bS = BT + (size_t)(colblk + r0) * EMBED + g0 * 8;

#define STG(SBUF, V) do { \
    const short* _a = aS + (V) * 64; \
    const short* _b = bS + (V) * 64; \
    async16(_a,         &As[SBUF][tid * 8]); \
    async16(_a + 65536, &As[SBUF][tid * 8 + 4096]); \
    async16(_b,         &Bs[SBUF][tid * 8]); \
    async16(_b + 65536, &Bs[SBUF][tid * 8 + 4096]); \
} while (0)

    f32x4 acc[4][2] = {};

    STG(0, 0);
    asm volatile("s_waitcnt vmcnt(0)" ::: "memory");
    __builtin_amdgcn_s_barrier();

    #pragma unroll 2
    for (int t = 0; t < 16; ++t) {
        const int cur = t & 1;
        if (t < 15) STG(cur ^ 1, t + 1);      // issue next-tile DMAs early
        bf16x8 af[4][2], bfv[2][2];
        #pragma unroll
        for (int fm = 0; fm < 4; ++fm) {
            const int row = wm * 64 + fm * 16 + c16;
            #pragma unroll
            for (int ks = 0; ks < 2; ++ks)
                af[fm][ks] = *(const bf16x8*)&As[cur][row * 64 + ((ks * 4 + quad) ^ sw) * 8];
        }
        #pragma unroll
        for (int fn = 0; fn < 2; ++fn) {
            const int col = wn * 32 + fn * 16 + c16;
            #pragma unroll
            for (int ks = 0; ks < 2; ++ks)
                bfv[fn][ks] = *(const bf16x8*)&Bs[cur][col * 64 + ((ks * 4 + quad) ^ sw) * 8];
        }
        __builtin_amdgcn_s_setprio(1);
        #pragma unroll
        for (int fm = 0; fm < 4; ++fm)
            #pragma unroll
            for (int fn = 0; fn < 2; ++fn)
                #pragma unroll
                for (int ks = 0; ks < 2; ++ks)
                    acc[fm][fn] = __builtin_amdgcn_mfma_f32_16x16x32_bf16(af[fm][ks], bfv[fn][ks], acc[fm][fn], 0, 0, 0);
        __builtin_amdgcn_s_setprio(0);
        asm volatile("s_waitcnt vmcnt(0)" ::: "memory");   // next tile landed (hidden under MFMA)
        __builtin_amdgcn_s_barrier();
    }

    // epilogue: C/D frag col = lane&15, row = quad*4 + reg
    const int rb0 = rowblk + wm * 64 + quad * 4;
    const int cb0 = colblk + wn * 32 + c16;
    #pragma unroll
    for (int fm = 0; fm < 4; ++fm) {
        const int row = rb0 + fm * 16;
        #pragma unroll
        for (int fn = 0; fn < 2; ++fn) {
            const int col = cb0 + fn * 16;
            const float bv = bias[col];
            #pragma unroll
            for (int r = 0; r < 4; ++r)
                C[(size_t)(row + r) * EMBED + col] = acc[fm][fn][r] + bv;
        }
    }
#undef STG
}

// ---------- MFMA flash attention v5.1 (unchanged — control: ~75 us,
// MfmaUtil 41 + VALUBusy 51 at 4 blocks/CU; cvt_pk P-pack). ----------
__global__ __launch_bounds__(256, 4) void attn_mfma(const short* __restrict__ Qb,
                                                    const short* __restrict__ Kb,
                                                    const short* __restrict__ Vt,
                                                    short* __restrict__ Ob) {
    __shared__ short SH[16384];      // kb[2] @ 0/4096, vb[2] @ 8192/12288 (shorts)
    const int tid = threadIdx.x;
    const int wave = tid >> 6, lane = tid & 63;
    const int l31 = lane & 31, h = lane >> 5;
    const int swz = l31 & 7;
    // T1 swizzle: grid (16 qb, 64 bh) = 1024 blocks
    const int hid = blockIdx.y * 16 + blockIdx.x;
    const int tle = (hid & 7) * 128 + (hid >> 3);
    const int qb = tle & 15, bh = tle >> 4;
    const int b = bh >> 4, hd = bh & 15;
    const size_t base = (size_t)b * SEQ * EMBED + (size_t)hd * HDIM;
    const size_t vbase = (size_t)bh * HDIM * SEQ;
    const int q0 = qb * 128;

    // Q B-frags for the whole kernel: n=q=l31, k(d) = ks*16 + h*8 + j
    bf16x8 qf[4];
    #pragma unroll
    for (int ks = 0; ks < 4; ++ks)
        qf[ks] = *(const bf16x8*)&Qb[base + (size_t)(q0 + wave * 32 + l31) * EMBED + ks * 16 + h * 8];

    // hoisted staging pointers (advance by constant per staged tile)
    const short* kp[2];
    const short* vp[2];
    int ldofs[2];
    #pragma unroll
    for (int it = 0; it < 2; ++it) {
        int ci = (it * 4 + wave) * 64 + lane;
        int row = ci >> 3, g = (ci & 7) ^ (row & 7);
        kp[it] = Kb + base + (size_t)row * EMBED + g * 8;
        vp[it] = Vt + vbase + (size_t)row * SEQ + g * 8;
        ldofs[it] = (it * 4 + wave) * 512;          // wave-uniform LDS base
    }

#define STAGE_KV(J) do { \
    async16(kp[0], &SH[(J) * 4096 + ldofs[0]]); \
    async16(kp[1], &SH[(J) * 4096 + ldofs[1]]); \
    async16(vp[0], &SH[8192 + (J) * 4096 + ldofs[0]]); \
    async16(vp[1], &SH[8192 + (J) * 4096 + ldofs[1]]); \
    kp[0] += 64 * EMBED; kp[1] += 64 * EMBED; \
    vp[0] += 64; vp[1] += 64; \
} while (0)

    f32x16 O[2] = {};
    f32x2 ls = {0.0f, 0.0f};

    // prologue: stage tile 0 into buf0
    STAGE_KV(0);
    asm volatile("s_waitcnt vmcnt(0)" ::: "memory");
    __builtin_amdgcn_s_barrier();

// One K/V tile from buffer CUR; optionally stage tile t+1 into buf NXT first.
// Per-nt half: QK(nt) 4 MFMA -> exp/pack (8 exp-pairs, 8 pk words via cvt_pk)
// -> PV steps ks=2nt,2nt+1 (4 MFMA).  S-liveness = one f32x16, pk = 8 regs.
#define ATT_TILE(CUR, NXT, DO_STAGE) do { \
    if (DO_STAGE) STAGE_KV(NXT); \
    _Pragma("unroll") \
    for (int nt = 0; nt < 2; ++nt) { \
        f32x16 st = {0.0f, 0.0f, 0.0f, 0.0f, 0.0f, 0.0f, 0.0f, 0.0f, \
                     0.0f, 0.0f, 0.0f, 0.0f, 0.0f, 0.0f, 0.0f, 0.0f}; \
        __builtin_amdgcn_s_setprio(1); \
        _Pragma("unroll") \
        for (int ks = 0; ks < 4; ++ks) { \
            bf16x8 ak = *(const bf16x8*)&SH[(CUR) * 4096 + (nt * 32 + l31) * 64 + ((ks * 2 + h) ^ swz) * 8]; \
            st = __builtin_amdgcn_mfma_f32_32x32x16_bf16(ak, qf[ks], st, 0, 0, 0); \
        } \
        __builtin_amdgcn_s_setprio(0); \
        u32 pk[8]; \
        _Pragma("unroll") \
        for (int i = 0; i < 8; ++i) { \
            float e0 = fexp2(st[2 * i]), e1 = fexp2(st[2 * i + 1]); \
            f32x2 e = { e0, e1 }; \
            ls += e; \
            pk[i] = cvtpk(e0, e1); \
        } \
        __builtin_amdgcn_s_setprio(1); \
        _Pragma("unroll") \
        for (int kk = 0; kk < 2; ++kk) { \
            const int ks = nt * 2 + kk, bs = kk * 4; \
            u32x4 fr; \
            i32x2 sA = __builtin_amdgcn_permlane32_swap((int)pk[bs + 0], (int)pk[bs + 2], false, false); \
            i32x2 sB = __builtin_amdgcn_permlane32_swap((int)pk[bs + 1], (int)pk[bs + 3], false, false); \
            fr.x = (u32)sA.x; fr.y = (u32)sB.x; fr.z = (u32)sA.y; fr.w = (u32)sB.y; \
            bf16x8 pf = __builtin_bit_cast(bf16x8, fr); \
            _Pragma("unroll") \
            for (int mt = 0; mt < 2; ++mt) { \
                bf16x8 vf = *(const bf16x8*)&SH[8192 + (CUR) * 4096 + (mt * 32 + l31) * 64 + ((ks * 2 + h) ^ swz) * 8]; \
                O[mt] = __builtin_amdgcn_mfma_f32_32x32x16_bf16(vf, pf, O[mt], 0, 0, 0); \
            } \
        } \
        __builtin_amdgcn_s_setprio(0); \
    } \
    asm volatile("s_waitcnt vmcnt(0)" ::: "memory"); \
    __builtin_amdgcn_s_barrier(); \
} while (0)

    // tiles 0..30 stage t+1; tile 31 computes only
    #pragma unroll 1
    for (int t = 0; t < 30; t += 2) {
        ATT_TILE(0, 1, 1);
        ATT_TILE(1, 0, 1);
    }
    ATT_TILE(0, 1, 1);   // t=30, stages 31 -> buf1
    ATT_TILE(1, 0, 0);   // t=31

#undef ATT_TILE
#undef STAGE_KV

    // finalize: partner lane holds the other half of this q's key-sum
    float lsum = ls.x + ls.y;
    lsum += __shfl_xor(lsum, 32);
    float inv = 1.0f / lsum;

    // O^T[d][q]: col=q=l31, d = mt*32 + (reg&3) + 8*(reg>>2) + 4h.
    // Write bf16 to LDS (XOR-swizzled 8B units), then read rows -> coalesced.
    const int wbase = wave * 2048;
    #pragma unroll
    for (int mt = 0; mt < 2; ++mt)
        #pragma unroll
        for (int m = 0; m < 4; ++m) {
            u32x2 wv;
            wv.x = pkbf(O[mt][4 * m + 0] * inv, O[mt][4 * m + 1] * inv);
            wv.y = pkbf(O[mt][4 * m + 2] * inv, O[mt][4 * m + 3] * inv);
            int u = mt * 8 + 2 * m + h;               // 8B unit index (d = u*4)
            int su = u ^ ((l31 & 7) << 1);
            *(u32x2*)&SH[wbase + l31 * 64 + su * 4] = wv;
        }
    __syncthreads();
    // full tile = 1024 x 16B chunks (4 waves x 32 q x 8 d-chunks)
    #pragma unroll
    for (int p = 0; p < 4; ++p) {
        int ci = p * 256 + tid;
        int wq = ci >> 8, rem = ci & 255;
        int r = rem >> 3, cch = rem & 7;
        int su = (2 * cch) ^ ((r & 7) << 1);
        bf16x8 val = *(const bf16x8*)&SH[wq * 2048 + r * 64 + su * 4];
        *(bf16x8*)&Ob[base + (size_t)(q0 + wq * 32 + r) * EMBED + cch * 8] = val;
    }
}

extern "C" void kernel_launch(void* const* d_in, const int* in_sizes, int n_in,
                              void* d_out, int out_size, void* d_ws, size_t ws_size,
                              hipStream_t stream)
{
    const float* X  = (const float*)d_in[0];
    const float* Wq = (const float*)d_in[1];
    const float* bq = (const float*)d_in[2];
    const float* Wk = (const float*)d_in[3];
    const float* bk = (const float*)d_in[4];
    const float* Wv = (const float*)d_in[5];
    const float* bv = (const float*)d_in[6];
    const float* Wo = (const float*)d_in[7];
    const float* bo = (const float*)d_in[8];
    float* out = (float*)d_out;

    const size_t NE = (size_t)ROWS * EMBED;       // 8M elements
    short* Xbf = (short*)d_ws;                    // 16 MB
    short* Qb  = Xbf + NE;                        // 16 MB (also attention O)
    short* Kb  = Qb + NE;                         // 16 MB
    short* Vtb = Kb + NE;                         // 16 MB  [bh][d][s]
    short* WqT = Vtb + NE;                        // 2 MB each; WqT/WkT/WvT are
    short* WkT = WqT + (size_t)EMBED * EMBED;     //   CONTIGUOUS = combined
    short* WvT = WkT + (size_t)EMBED * EMBED;     //   Wqkv^T [3072][1024]
    short* WoT = WvT + (size_t)EMBED * EMBED;     // total 72 MB

    // fused convert + weight transpose: 8192 + 1024 blocks, one dispatch
    prep<<<9216, 256, 0, stream>>>(X, Xbf, Wq, Wk, Wv, Wo, WqT, WkT, WvT, WoT);

    // combined QKV: grid (3072/256, 8192/128) = 768 blocks = 3 exact rounds
    dim3 gq(12, 64, 1);
    gemm_p128<<<gq, 512, 0, stream>>>(Xbf, WqT, bq, bk, bv, Qb, Kb, Vtb, 0);

    dim3 gt(SEQ / 128, BATCH * NHEADS);           // (16, 64)
    attn_mfma<<<gt, 256, 0, stream>>>(Qb, Kb, Vtb, Qb);   // O aliases Qb

    // out-proj: grid (1024/128, 8192/128) = 512 blocks = 2 blocks/CU
    dim3 gg(8, 64, 1);
    gemm_k64<<<gg, 512, 0, stream>>>(Qb, WoT, bo, out);
    // R22 INSTRUMENTATION: idempotent duplicate — measures out-proj duration
    // via total-delta vs the 255.9-us R20 config (fork pre-committed above).
    gemm_k64<<<gg, 512, 0, stream>>>(Qb, WoT, bo, out);
}

// Round 14
// 248.352 us; speedup vs baseline: 1.3276x; 1.1078x over previous
//
#include <hip/hip_runtime.h>
#include <hip/hip_bf16.h>

#define EMBED 1024
#define NHEADS 16
#define HDIM 64
#define SEQ 2048
#define BATCH 4
#define ROWS (BATCH * SEQ) /* 8192 */

typedef __attribute__((ext_vector_type(8))) short bf16x8;   // 8 bf16 = 4 VGPRs
typedef __attribute__((ext_vector_type(4))) float f32x4;
typedef __attribute__((ext_vector_type(2))) float f32x2;
typedef __attribute__((ext_vector_type(16))) float f32x16;
typedef __attribute__((ext_vector_type(4))) unsigned int u32x4;
typedef __attribute__((ext_vector_type(2))) unsigned int u32x2;
typedef __attribute__((ext_vector_type(2))) int i32x2;
typedef unsigned int u32;

#define SL2E 0.18033688011112042f  /* 0.125 * log2(e) */

__device__ __forceinline__ short f2bf(float f) {            // RTNA fp32->bf16 (2 ops)
    u32 u = __builtin_bit_cast(u32, f) + 0x8000u;
    return (short)(u >> 16);
}

__device__ __forceinline__ u32 pkbf(float a, float b) {     // {bf16(a)|bf16(b)<<16}, 3 ops
    u32 ua = __builtin_bit_cast(u32, a) + 0x8000u;
    u32 ub = __builtin_bit_cast(u32, b) + 0x8000u;
    return __builtin_amdgcn_perm(ua, ub, 0x03020706u);      // v_perm_b32: {a.hi16, b.hi16}
}

// single-instruction packed cvt (RTNE): a -> low16, b -> high16 (same order as pkbf)
__device__ __forceinline__ u32 cvtpk(float a, float b) {
    u32 r;
    asm("v_cvt_pk_bf16_f32 %0, %1, %2" : "=v"(r) : "v"(a), "v"(b));
    return r;
}

__device__ __forceinline__ float fexp2(float x) {
#if __has_builtin(__builtin_amdgcn_exp2f)
    return __builtin_amdgcn_exp2f(x);                       // bare v_exp_f32
#else
    return exp2f(x);
#endif
}

__device__ __forceinline__ void async16(const void* g, void* l) {
    __builtin_amdgcn_global_load_lds((const __attribute__((address_space(1))) u32*)g,
                                     (__attribute__((address_space(3))) u32*)l, 16, 0, 0);
}

// ---------- R18 fused prep: X fp32->bf16 (blocks 0..8191) + W transpose
// (blocks 8192..9215). ----------
__global__ __launch_bounds__(256) void prep(const float* __restrict__ X,
                                            short* __restrict__ Xbf,
                                            const float* __restrict__ W0,
                                            const float* __restrict__ W1,
                                            const float* __restrict__ W2,
                                            const float* __restrict__ W3,
                                            short* __restrict__ T0,
                                            short* __restrict__ T1,
                                            short* __restrict__ T2,
                                            short* __restrict__ T3) {
    const int bid = blockIdx.x;
    if (bid < 8192) {
        int i = (bid * 256 + threadIdx.x) * 4;
        float4 v = *(const float4*)&X[i];
        u32x2 o = { pkbf(v.x, v.y), pkbf(v.z, v.w) };
        *(u32x2*)&Xbf[i] = o;
        return;
    }
    const int id = bid - 8192;                 // 0..1023
    const int z = id >> 8;
    const int rem = id & 255;
    const int n0 = (rem & 15) * 64, k0 = (rem >> 4) * 64;
    const float* W = (z == 0) ? W0 : (z == 1) ? W1 : (z == 2) ? W2 : W3;
    short* WT = (z == 0) ? T0 : (z == 1) ? T1 : (z == 2) ? T2 : T3;
    const float sc = (z == 0) ? SL2E : 1.0f;
    __shared__ float T[64][65];
    const int rr = threadIdx.x >> 4, cc = (threadIdx.x & 15) * 4;
    #pragma unroll
    for (int p = 0; p < 4; ++p) {
        int r = p * 16 + rr;
        float4 v = *(const float4*)&W[(size_t)(k0 + r) * EMBED + n0 + cc];
        T[r][cc] = v.x * sc; T[r][cc + 1] = v.y * sc; T[r][cc + 2] = v.z * sc; T[r][cc + 3] = v.w * sc;
    }
    __syncthreads();
    #pragma unroll
    for (int p = 0; p < 4; ++p) {
        int r = p * 16 + rr;  // n offset
        u32x2 o = { pkbf(T[cc][r], T[cc + 1][r]), pkbf(T[cc + 2][r], T[cc + 3][r]) };
        *(u32x2*)&WT[(size_t)(n0 + r) * EMBED + k0 + cc] = o;
    }
}

// ============================================================================
// R23 QKV GEMM: k64-structure port (R22 measured k64 at 895 TF vs p128's
// 698 TF — simple dbuf + 2 blk/CU cross-block TLP beats the 4-phase lockstep
// at 1 blk/CU).  128x128 tile, 8 waves (2M x 4N, 64x32/wave), BK=64, LDS
// 64 KiB dbuf -> 2 blocks/CU; grid (24,64) = 1536 blocks = 3 exact rounds.
// T1 swizzle: consecutive hid share the A row-panel -> L2 reuse per XCD.
// Per tile: stage(t+1) -> other buf, compute t (16 MFMA/wave), one
// vmcnt(0)+s_barrier (drain hidden under MFMA + covered by co-resident blk).
// Epilogue (QKV): 128-col blocks never straddle Q/K/V (1024%128==0);
// z = colblk>>10 -> Q bf16 (bias pre-scaled SL2E) / K bf16 / Vt[bh][d][s].
// ============================================================================
__global__ __launch_bounds__(512, 2) void gemm_qkv128(const short* __restrict__ A,
                                                      const short* __restrict__ BT,
                                                      const float* __restrict__ b0,
                                                      const float* __restrict__ b1,
                                                      const float* __restrict__ b2,
                                                      short* __restrict__ Cq,
                                                      short* __restrict__ Ck,
                                                      short* __restrict__ Vt) {
    __shared__ short As[2][8192];    // [buf][128 rows][64 k], 16 KB each
    __shared__ short Bs[2][8192];    // [buf][128 cols][64 k]
    const int tid = threadIdx.x;
    const int lane = tid & 63, wid = tid >> 6;
    const int c16 = lane & 15, quad = lane >> 4, sw = c16 & 7;
    const int wm = wid >> 2, wn = wid & 3;    // per-wave 64 rows x 32 cols
    // T1 swizzle: 1536 blocks, % 8 == 0
    const int gx = gridDim.x;
    const int hid = blockIdx.y * gx + blockIdx.x;
    const int cpx = (gx * gridDim.y) >> 3;
    const int tle = (hid & 7) * cpx + (hid >> 3);
    const int bx = tle % gx, by = tle / gx;
    const int rowblk = by * 128, colblk = bx * 128;

    const int r0 = tid >> 3;                  // 0..63
    const int g0 = (tid & 7) ^ (r0 & 7);
    const short* aS = A + (size_t)(rowblk + r0) * EMBED + g0 * 8;
    const short* bS = BT + (size_t)(colblk + r0) * EMBED + g0 * 8;

#define STG(SBUF, V) do { \
    const short* _a = aS + (V) * 64; \
    const short* _b = bS + (V) * 64; \
    async16(_a,         &As[SBUF][tid * 8]); \
    async16(_a + 65536, &As[SBUF][tid * 8 + 4096]); \
    async16(_b,         &Bs[SBUF][tid * 8]); \
    async16(_b + 65536, &Bs[SBUF][tid * 8 + 4096]); \
} while (0)

    f32x4 acc[4][2] = {};

    STG(0, 0);
    asm volatile("s_waitcnt vmcnt(0)" ::: "memory");
    __builtin_amdgcn_s_barrier();

    #pragma unroll 2
    for (int t = 0; t < 16; ++t) {
        const int cur = t & 1;
        if (t < 15) STG(cur ^ 1, t + 1);      // issue next-tile DMAs early
        bf16x8 af[4][2], bfv[2][2];
        #pragma unroll
        for (int fm = 0; fm < 4; ++fm) {
            const int row = wm * 64 + fm * 16 + c16;
            #pragma unroll
            for (int ks = 0; ks < 2; ++ks)
                af[fm][ks] = *(const bf16x8*)&As[cur][row * 64 + ((ks * 4 + quad) ^ sw) * 8];
        }
        #pragma unroll
        for (int fn = 0; fn < 2; ++fn) {
            const int col = wn * 32 + fn * 16 + c16;
            #pragma unroll
            for (int ks = 0; ks < 2; ++ks)
                bfv[fn][ks] = *(const bf16x8*)&Bs[cur][col * 64 + ((ks * 4 + quad) ^ sw) * 8];
        }
        __builtin_amdgcn_s_setprio(1);
        #pragma unroll
        for (int fm = 0; fm < 4; ++fm)
            #pragma unroll
            for (int fn = 0; fn < 2; ++fn)
                #pragma unroll
                for (int ks = 0; ks < 2; ++ks)
                    acc[fm][fn] = __builtin_amdgcn_mfma_f32_16x16x32_bf16(af[fm][ks], bfv[fn][ks], acc[fm][fn], 0, 0, 0);
        __builtin_amdgcn_s_setprio(0);
        asm volatile("s_waitcnt vmcnt(0)" ::: "memory");   // next tile landed (hidden under MFMA)
        __builtin_amdgcn_s_barrier();
    }

    // epilogue: C/D frag col = lane&15, row = quad*4 + reg
    const int rb0 = rowblk + wm * 64 + quad * 4;
    const int z = colblk >> 10;               // Q / K / V selector
    const int cm = colblk & 1023;
    const int cb0 = cm + wn * 32 + c16;
    const float* bias = (z == 0) ? b0 : (z == 1) ? b1 : b2;
    if (z == 2) {
        // V -> Vt[bh][d][s]; 4 acc regs = 4 consecutive s
        #pragma unroll
        for (int fm = 0; fm < 4; ++fm) {
            const int row = rb0 + fm * 16;
            const int b = row >> 11, s = row & 2047;
            #pragma unroll
            for (int fn = 0; fn < 2; ++fn) {
                const int cv = cb0 + fn * 16;
                const int head = cv >> 6, d = cv & 63;
                const float bv = bias[cv];
                u32x2 o = { pkbf(acc[fm][fn][0] + bv, acc[fm][fn][1] + bv),
                            pkbf(acc[fm][fn][2] + bv, acc[fm][fn][3] + bv) };
                *(u32x2*)&Vt[((size_t)(b * NHEADS + head) * HDIM + d) * SEQ + s] = o;
            }
        }
    } else {
        short* Cout = (z == 0) ? Cq : Ck;
        const float bsc = (z == 0) ? SL2E : 1.0f;
        #pragma unroll
        for (int fm = 0; fm < 4; ++fm) {
            const int row = rb0 + fm * 16;
            #pragma unroll
            for (int fn = 0; fn < 2; ++fn) {
                const int col = cb0 + fn * 16;
                const float bv = bias[col] * bsc;
                #pragma unroll
                for (int r = 0; r < 4; ++r)
                    Cout[(size_t)(row + r) * EMBED + col] = f2bf(acc[fm][fn][r] + bv);
            }
        }
    }
#undef STG
}

// ============================================================================
// R20 out-proj GEMM (unchanged — measured 19.2 us / 895 TF in R22):
// 128x128 tile, 8 waves, BK=64, LDS 64 KiB dbuf, 2 blocks/CU.
// ============================================================================
__global__ __launch_bounds__(512, 2) void gemm_k64(const short* __restrict__ A,
                                                   const short* __restrict__ BT,
                                                   const float* __restrict__ bias,
                                                   float* __restrict__ C) {
    __shared__ short As[2][8192];    // [buf][128 rows][64 k], 16 KB each
    __shared__ short Bs[2][8192];    // [buf][128 cols][64 k]
    const int tid = threadIdx.x;
    const int lane = tid & 63, wid = tid >> 6;
    const int c16 = lane & 15, quad = lane >> 4, sw = c16 & 7;
    const int wm = wid >> 2, wn = wid & 3;    // per-wave 64 rows x 32 cols
    // T1 swizzle: 512 blocks, % 8 == 0
    const int gx = gridDim.x;
    const int hid = blockIdx.y * gx + blockIdx.x;
    const int cpx = (gx * gridDim.y) >> 3;
    const int tle = (hid & 7) * cpx + (hid >> 3);
    const int bx = tle % gx, by = tle / gx;
    const int rowblk = by * 128, colblk = bx * 128;

    const int r0 = tid >> 3;                  // 0..63
    const int g0 = (tid & 7) ^ (r0 & 7);
    const short* aS = A + (size_t)(rowblk + r0) * EMBED + g0 * 8;
    const short* bS = BT + (size_t)(colblk + r0) * EMBED + g0 * 8;

#define STG(SBUF, V) do { \
    const short* _a = aS + (V) * 64; \
    const short* _b = bS + (V) * 64; \
    async16(_a,         &As[SBUF][tid * 8]); \
    async16(_a + 65536, &As[SBUF][tid * 8 + 4096]); \
    async16(_b,         &Bs[SBUF][tid * 8]); \
    async16(_b + 65536, &Bs[SBUF][tid * 8 + 4096]); \
} while (0)

    f32x4 acc[4][2] = {};

    STG(0, 0);
    asm volatile("s_waitcnt vmcnt(0)" ::: "memory");
    __builtin_amdgcn_s_barrier();

    #pragma unroll 2
    for (int t = 0; t < 16; ++t) {
        const int cur = t & 1;
        if (t < 15) STG(cur ^ 1, t + 1);      // issue next-tile DMAs early
        bf16x8 af[4][2], bfv[2][2];
        #pragma unroll
        for (int fm = 0; fm < 4; ++fm) {
            const int row = wm * 64 + fm * 16 + c16;
            #pragma unroll
            for (int ks = 0; ks < 2; ++ks)
                af[fm][ks] = *(const bf16x8*)&As[cur][row * 64 + ((ks * 4 + quad) ^ sw) * 8];
        }
        #pragma unroll
        for (int fn = 0; fn < 2; ++fn) {
            const int col = wn * 32 + fn * 16 + c16;
            #pragma unroll
            for (int ks = 0; ks < 2; ++ks)
                bfv[fn][ks] = *(const bf16x8*)&Bs[cur][col * 64 + ((ks * 4 + quad) ^ sw) * 8];
        }
        __builtin_amdgcn_s_setprio(1);
        #pragma unroll
        for (int fm = 0; fm < 4; ++fm)
            #pragma unroll
            for (int fn = 0; fn < 2; ++fn)
                #pragma unroll
                for (int ks = 0; ks < 2; ++ks)
                    acc[fm][fn] = __builtin_amdgcn_mfma_f32_16x16x32_bf16(af[fm][ks], bfv[fn][ks], acc[fm][fn], 0, 0, 0);
        __builtin_amdgcn_s_setprio(0);
        asm volatile("s_waitcnt vmcnt(0)" ::: "memory");   // next tile landed (hidden under MFMA)
        __builtin_amdgcn_s_barrier();
    }

    // epilogue: C/D frag col = lane&15, row = quad*4 + reg
    const int rb0 = rowblk + wm * 64 + quad * 4;
    const int cb0 = colblk + wn * 32 + c16;
    #pragma unroll
    for (int fm = 0; fm < 4; ++fm) {
        const int row = rb0 + fm * 16;
        #pragma unroll
        for (int fn = 0; fn < 2; ++fn) {
            const int col = cb0 + fn * 16;
            const float bv = bias[col];
            #pragma unroll
            for (int r = 0; r < 4; ++r)
                C[(size_t)(row + r) * EMBED + col] = acc[fm][fn][r] + bv;
        }
    }
#undef STG
}

// ---------- MFMA flash attention v5.1 (unchanged — control: ~75.8 us,
// MfmaUtil 41 + VALUBusy 50 at 4 blocks/CU; cvt_pk P-pack). ----------
__global__ __launch_bounds__(256, 4) void attn_mfma(const short* __restrict__ Qb,
                                                    const short* __restrict__ Kb,
                                                    const short* __restrict__ Vt,
                                                    short* __restrict__ Ob) {
    __shared__ short SH[16384];      // kb[2] @ 0/4096, vb[2] @ 8192/12288 (shorts)
    const int tid = threadIdx.x;
    const int wave = tid >> 6, lane = tid & 63;
    const int l31 = lane & 31, h = lane >> 5;
    const int swz = l31 & 7;
    // T1 swizzle: grid (16 qb, 64 bh) = 1024 blocks
    const int hid = blockIdx.y * 16 + blockIdx.x;
    const int tle = (hid & 7) * 128 + (hid >> 3);
    const int qb = tle & 15, bh = tle >> 4;
    const int b = bh >> 4, hd = bh & 15;
    const size_t base = (size_t)b * SEQ * EMBED + (size_t)hd * HDIM;
    const size_t vbase = (size_t)bh * HDIM * SEQ;
    const int q0 = qb * 128;

    // Q B-frags for the whole kernel: n=q=l31, k(d) = ks*16 + h*8 + j
    bf16x8 qf[4];
    #pragma unroll
    for (int ks = 0; ks < 4; ++ks)
        qf[ks] = *(const bf16x8*)&Qb[base + (size_t)(q0 + wave * 32 + l31) * EMBED + ks * 16 + h * 8];

    // hoisted staging pointers (advance by constant per staged tile)
    const short* kp[2];
    const short* vp[2];
    int ldofs[2];
    #pragma unroll
    for (int it = 0; it < 2; ++it) {
        int ci = (it * 4 + wave) * 64 + lane;
        int row = ci >> 3, g = (ci & 7) ^ (row & 7);
        kp[it] = Kb + base + (size_t)row * EMBED + g * 8;
        vp[it] = Vt + vbase + (size_t)row * SEQ + g * 8;
        ldofs[it] = (it * 4 + wave) * 512;          // wave-uniform LDS base
    }

#define STAGE_KV(J) do { \
    async16(kp[0], &SH[(J) * 4096 + ldofs[0]]); \
    async16(kp[1], &SH[(J) * 4096 + ldofs[1]]); \
    async16(vp[0], &SH[8192 + (J) * 4096 + ldofs[0]]); \
    async16(vp[1], &SH[8192 + (J) * 4096 + ldofs[1]]); \
    kp[0] += 64 * EMBED; kp[1] += 64 * EMBED; \
    vp[0] += 64; vp[1] += 64; \
} while (0)

    f32x16 O[2] = {};
    f32x2 ls = {0.0f, 0.0f};

    // prologue: stage tile 0 into buf0
    STAGE_KV(0);
    asm volatile("s_waitcnt vmcnt(0)" ::: "memory");
    __builtin_amdgcn_s_barrier();

// One K/V tile from buffer CUR; optionally stage tile t+1 into buf NXT first.
// Per-nt half: QK(nt) 4 MFMA -> exp/pack (8 exp-pairs, 8 pk words via cvt_pk)
// -> PV steps ks=2nt,2nt+1 (4 MFMA).  S-liveness = one f32x16, pk = 8 regs.
#define ATT_TILE(CUR, NXT, DO_STAGE) do { \
    if (DO_STAGE) STAGE_KV(NXT); \
    _Pragma("unroll") \
    for (int nt = 0; nt < 2; ++nt) { \
        f32x16 st = {0.0f, 0.0f, 0.0f, 0.0f, 0.0f, 0.0f, 0.0f, 0.0f, \
                     0.0f, 0.0f, 0.0f, 0.0f, 0.0f, 0.0f, 0.0f, 0.0f}; \
        __builtin_amdgcn_s_setprio(1); \
        _Pragma("unroll") \
        for (int ks = 0; ks < 4; ++ks) { \
            bf16x8 ak = *(const bf16x8*)&SH[(CUR) * 4096 + (nt * 32 + l31) * 64 + ((ks * 2 + h) ^ swz) * 8]; \
            st = __builtin_amdgcn_mfma_f32_32x32x16_bf16(ak, qf[ks], st, 0, 0, 0); \
        } \
        __builtin_amdgcn_s_setprio(0); \
        u32 pk[8]; \
        _Pragma("unroll") \
        for (int i = 0; i < 8; ++i) { \
            float e0 = fexp2(st[2 * i]), e1 = fexp2(st[2 * i + 1]); \
            f32x2 e = { e0, e1 }; \
            ls += e; \
            pk[i] = cvtpk(e0, e1); \
        } \
        __builtin_amdgcn_s_setprio(1); \
        _Pragma("unroll") \
        for (int kk = 0; kk < 2; ++kk) { \
            const int ks = nt * 2 + kk, bs = kk * 4; \
            u32x4 fr; \
            i32x2 sA = __builtin_amdgcn_permlane32_swap((int)pk[bs + 0], (int)pk[bs + 2], false, false); \
            i32x2 sB = __builtin_amdgcn_permlane32_swap((int)pk[bs + 1], (int)pk[bs + 3], false, false); \
            fr.x = (u32)sA.x; fr.y = (u32)sB.x; fr.z = (u32)sA.y; fr.w = (u32)sB.y; \
            bf16x8 pf = __builtin_bit_cast(bf16x8, fr); \
            _Pragma("unroll") \
            for (int mt = 0; mt < 2; ++mt) { \
                bf16x8 vf = *(const bf16x8*)&SH[8192 + (CUR) * 4096 + (mt * 32 + l31) * 64 + ((ks * 2 + h) ^ swz) * 8]; \
                O[mt] = __builtin_amdgcn_mfma_f32_32x32x16_bf16(vf, pf, O[mt], 0, 0, 0); \
            } \
        } \
        __builtin_amdgcn_s_setprio(0); \
    } \
    asm volatile("s_waitcnt vmcnt(0)" ::: "memory"); \
    __builtin_amdgcn_s_barrier(); \
} while (0)

    // tiles 0..30 stage t+1; tile 31 computes only
    #pragma unroll 1
    for (int t = 0; t < 30; t += 2) {
        ATT_TILE(0, 1, 1);
        ATT_TILE(1, 0, 1);
    }
    ATT_TILE(0, 1, 1);   // t=30, stages 31 -> buf1
    ATT_TILE(1, 0, 0);   // t=31

#undef ATT_TILE
#undef STAGE_KV

    // finalize: partner lane holds the other half of this q's key-sum
    float lsum = ls.x + ls.y;
    lsum += __shfl_xor(lsum, 32);
    float inv = 1.0f / lsum;

    // O^T[d][q]: col=q=l31, d = mt*32 + (reg&3) + 8*(reg>>2) + 4h.
    // Write bf16 to LDS (XOR-swizzled 8B units), then read rows -> coalesced.
    const int wbase = wave * 2048;
    #pragma unroll
    for (int mt = 0; mt < 2; ++mt)
        #pragma unroll
        for (int m = 0; m < 4; ++m) {
            u32x2 wv;
            wv.x = pkbf(O[mt][4 * m + 0] * inv, O[mt][4 * m + 1] * inv);
            wv.y = pkbf(O[mt][4 * m + 2] * inv, O[mt][4 * m + 3] * inv);
            int u = mt * 8 + 2 * m + h;               // 8B unit index (d = u*4)
            int su = u ^ ((l31 & 7) << 1);
            *(u32x2*)&SH[wbase + l31 * 64 + su * 4] = wv;
        }
    __syncthreads();
    // full tile = 1024 x 16B chunks (4 waves x 32 q x 8 d-chunks)
    #pragma unroll
    for (int p = 0; p < 4; ++p) {
        int ci = p * 256 + tid;
        int wq = ci >> 8, rem = ci & 255;
        int r = rem >> 3, cch = rem & 7;
        int su = (2 * cch) ^ ((r & 7) << 1);
        bf16x8 val = *(const bf16x8*)&SH[wq * 2048 + r * 64 + su * 4];
        *(bf16x8*)&Ob[base + (size_t)(q0 + wq * 32 + r) * EMBED + cch * 8] = val;
    }
}

extern "C" void kernel_launch(void* const* d_in, const int* in_sizes, int n_in,
                              void* d_out, int out_size, void* d_ws, size_t ws_size,
                              hipStream_t stream)
{
    const float* X  = (const float*)d_in[0];
    const float* Wq = (const float*)d_in[1];
    const float* bq = (const float*)d_in[2];
    const float* Wk = (const float*)d_in[3];
    const float* bk = (const float*)d_in[4];
    const float* Wv = (const float*)d_in[5];
    const float* bv = (const float*)d_in[6];
    const float* Wo = (const float*)d_in[7];
    const float* bo = (const float*)d_in[8];
    float* out = (float*)d_out;

    const size_t NE = (size_t)ROWS * EMBED;       // 8M elements
    short* Xbf = (short*)d_ws;                    // 16 MB
    short* Qb  = Xbf + NE;                        // 16 MB (also attention O)
    short* Kb  = Qb + NE;                         // 16 MB
    short* Vtb = Kb + NE;                         // 16 MB  [bh][d][s]
    short* WqT = Vtb + NE;                        // 2 MB each; WqT/WkT/WvT are
    short* WkT = WqT + (size_t)EMBED * EMBED;     //   CONTIGUOUS = combined
    short* WvT = WkT + (size_t)EMBED * EMBED;     //   Wqkv^T [3072][1024]
    short* WoT = WvT + (size_t)EMBED * EMBED;     // total 72 MB

    // fused convert + weight transpose: 8192 + 1024 blocks, one dispatch
    prep<<<9216, 256, 0, stream>>>(X, Xbf, Wq, Wk, Wv, Wo, WqT, WkT, WvT, WoT);

    // combined QKV via k64-structure: grid (3072/128, 8192/128) = 1536 blocks
    // = 3 exact 2-blk/CU rounds
    dim3 gq(24, 64, 1);
    gemm_qkv128<<<gq, 512, 0, stream>>>(Xbf, WqT, bq, bk, bv, Qb, Kb, Vtb);

    dim3 gt(SEQ / 128, BATCH * NHEADS);           // (16, 64)
    attn_mfma<<<gt, 256, 0, stream>>>(Qb, Kb, Vtb, Qb);   // O aliases Qb

    // out-proj: grid (1024/128, 8192/128) = 512 blocks = 2 blocks/CU
    dim3 gg(8, 64, 1);
    gemm_k64<<<gg, 512, 0, stream>>>(Qb, WoT, bo, out);
}